// Round 5
// baseline (5858.668 us; speedup 1.0000x reference)
//
#include <hip/hip_runtime.h>
#include <hip/hip_bf16.h>

// Problem dims (fixed)
#define NA   128   // agents
#define NN_  16    // neighbors
#define SS   64    // timesteps
#define DD   128   // model dim
#define HH   4     // heads

// ---------------------------------------------------------------------------
// Mask dtype probe (kept for robustness; R3/R4 A/B showed word-mode = int32).
// ---------------------------------------------------------------------------
__global__ void k_maskmode(const unsigned int* __restrict__ m, int* __restrict__ flag)
{
    __shared__ int f;
    if (threadIdx.x == 0) f = 0;
    __syncthreads();
    for (int i = threadIdx.x; i < 4096; i += 256) {
        if (m[i] & 0xFFFFFF00u) f = 1;  // benign race, all writers write 1
    }
    __syncthreads();
    if (threadIdx.x == 0) *flag = f;
}

// ---------------------------------------------------------------------------
// Kernel 1: per (bn, h) block. Q/K/V proj, masked softmax, att_sum atomics,
// res_h = attn @ V_h -> res (fp32, staged in d_out's nb region: exact element
// count match; k_mha_ffn consumes per-block before overwriting).
// ---------------------------------------------------------------------------
__global__ __launch_bounds__(256) void k_attn(
    const float* __restrict__ nbr,            // (2048,64,128) fp32
    const void* __restrict__ mask,            // (2048,64,64) int32 (probed)
    const int* __restrict__ mflag,
    const float* __restrict__ Wq,             // (128,128)
    const float* __restrict__ Wk,
    const float* __restrict__ Wv,
    float* __restrict__ att_sum,              // (128,4,64,64) fp32, pre-zeroed
    float* res_ws)                            // (2048,64,128) fp32 (aliases out_nb)
{
    const int bnh = blockIdx.x;
    const int h   = bnh & 3;
    const int bn  = bnh >> 2;
    const int b   = bn >> 4;
    const int tid = threadIdx.x;

    __shared__ float Esh[64 * 128];          // 32 KB, reused as Sc (16 KB)
    __shared__ float Qh[64 * 32];            // 8 KB
    __shared__ float Kh[64 * 32];            // 8 KB
    __shared__ float Vh[64 * 32];            // 8 KB   total 56 KB
    float* const Sc = Esh;                   // alias: scores live where E was

    const float* E = nbr + (size_t)bn * 64 * 128;
    for (int i = tid; i < 64 * 128; i += 256) Esh[i] = E[i];
    __syncthreads();

    const int col = h * 32;
    for (int i = tid; i < 64 * 32; i += 256) {
        const int s = i >> 5, k = i & 31;
        const float* er = Esh + s * 128;
        const float* wq = Wq + col + k;
        const float* wk = Wk + col + k;
        const float* wv = Wv + col + k;
        float aq = 0.f, ak = 0.f, av = 0.f;
        for (int d = 0; d < 128; ++d) {
            const float e = er[d];
            aq += e * wq[d * 128];
            ak += e * wk[d * 128];
            av += e * wv[d * 128];
        }
        Qh[i] = aq; Kh[i] = ak; Vh[i] = av;
    }
    __syncthreads();   // Esh dead -> Sc may overwrite

    const int bytemode = *mflag;
    const float iscale = 0.17677669529663687f; // 1/sqrt(32)
    const int* mrow32 = (const int*)mask + (size_t)bn * 4096;
    const unsigned char* mrow8 = (const unsigned char*)mask + (size_t)bn * 4096;
    for (int i = tid; i < 4096; i += 256) {
        const int s = i >> 6, t = i & 63;
        const float* qs = Qh + s * 32;
        const float* kt = Kh + t * 32;
        float acc = 0.f;
#pragma unroll 8
        for (int k = 0; k < 32; ++k) acc += qs[k] * kt[k];
        const int mv = bytemode ? (int)mrow8[i] : mrow32[i];
        Sc[i] = mv ? acc * iscale : -1e9f;
    }
    __syncthreads();

    if (tid < 64) {
        float* r = Sc + tid * 64;
        float m = r[0];
        for (int t = 1; t < 64; ++t) m = fmaxf(m, r[t]);
        float sum = 0.f;
        for (int t = 0; t < 64; ++t) { const float e = __expf(r[t] - m); r[t] = e; sum += e; }
        const float inv = 1.f / sum;
        for (int t = 0; t < 64; ++t) r[t] *= inv;
    }
    __syncthreads();

    float* as = att_sum + ((size_t)(b * 4 + h)) * 4096;
    for (int i = tid; i < 4096; i += 256) atomicAdd(as + i, Sc[i]);

    for (int i = tid; i < 2048; i += 256) {
        const int s = i >> 5, d = i & 31;
        const float* sr = Sc + s * 64;
        const float* vc = Vh + d;
        float acc = 0.f;
        for (int t = 0; t < 64; ++t) acc += sr[t] * vc[t * 32];
        res_ws[((size_t)bn * 64 + s) * 128 + h * 32 + d] = acc;
    }
}

// ---------------------------------------------------------------------------
// Shared FFN + LN epilogue: out = LN(relu(X @ W1) @ W2 + X) * g + b  (fp32 out)
// ---------------------------------------------------------------------------
__device__ __forceinline__ void ffn_ln_store(
    const float* __restrict__ shX, float* __restrict__ tb_all,
    const float* __restrict__ W1, const float* __restrict__ W2,
    const float* __restrict__ g, const float* __restrict__ bb,
    float* outp)
{
    const int tid = threadIdx.x;
    const int w = tid >> 6;
    const int lane = tid & 63;
    float* tb = tb_all + w * 512;
    const int j0 = lane * 2, j1 = lane * 2 + 1;
    const float gj0 = g[j0], gj1 = g[j1];
    const float bj0 = bb[j0], bj1 = bb[j1];

    for (int it = 0; it < 16; ++it) {
        const int r = w * 16 + it;
        const float* xr = shX + r * 128;
        float a[8];
#pragma unroll
        for (int ff = 0; ff < 8; ++ff) a[ff] = 0.f;
        const float* w1p = W1 + lane * 8;
        for (int d = 0; d < 128; ++d) {
            const float xv = xr[d];
            const float* wr = w1p + d * 512;
#pragma unroll
            for (int ff = 0; ff < 8; ++ff) a[ff] += xv * wr[ff];
        }
#pragma unroll
        for (int ff = 0; ff < 8; ++ff) tb[lane * 8 + ff] = fmaxf(a[ff], 0.f);
        __syncthreads();

        float o0 = xr[j0], o1 = xr[j1]; // residual
        for (int f = 0; f < 512; ++f) {
            const float tv = tb[f];
            const float* wr = W2 + f * 128;
            o0 += tv * wr[j0];
            o1 += tv * wr[j1];
        }
        float ps = o0 + o1;
#pragma unroll
        for (int off = 32; off > 0; off >>= 1) ps += __shfl_xor(ps, off, 64);
        const float mean = ps * (1.f / 128.f);
        const float d0 = o0 - mean, d1 = o1 - mean;
        float pq = d0 * d0 + d1 * d1;
#pragma unroll
        for (int off = 32; off > 0; off >>= 1) pq += __shfl_xor(pq, off, 64);
        const float rstd = rsqrtf(pq * (1.f / 128.f) + 1e-5f);
        outp[r * 128 + j0] = d0 * rstd * gj0 + bj0;
        outp[r * 128 + j1] = d1 * rstd * gj1 + bj1;
        __syncthreads();
    }
}

// ---------------------------------------------------------------------------
// Kernel 2: per bn. O = res @ W_fc + E; LN; FFN+LN -> nb (fp32).
// res_in / out_nb alias the SAME fp32 region (element-exact): each block
// fully reads its own slice into LDS (barrier) before any store.
// ---------------------------------------------------------------------------
__global__ __launch_bounds__(256) void k_mha_ffn(
    const float* __restrict__ nbr,
    const float* res_in,                      // aliases out_nb
    const float* __restrict__ Wfc,
    const float* __restrict__ g1, const float* __restrict__ b1,
    const float* __restrict__ W1, const float* __restrict__ W2,
    const float* __restrict__ g2, const float* __restrict__ b2,
    float* out_nb)                            // aliases res_in
{
    const int bn = blockIdx.x;
    const int tid = threadIdx.x;
    __shared__ float shR[64 * 128];  // 32 KB
    __shared__ float tbuf[4 * 512];  // 8 KB

    const float* rp = res_in + (size_t)bn * 8192;
    for (int i = tid; i < 8192; i += 256) shR[i] = rp[i];
    __syncthreads();

    const int s = tid >> 2, q = tid & 3;
    const float* Erow = nbr + ((size_t)bn * 64 + s) * 128 + q * 32;
    float O[32];
#pragma unroll
    for (int jj = 0; jj < 32; ++jj) O[jj] = Erow[jj]; // residual
    const float* rr = shR + s * 128;
    for (int k = 0; k < 128; ++k) {
        const float rv = rr[k];
        const float* wr = Wfc + k * 128 + q * 32;
#pragma unroll 8
        for (int jj = 0; jj < 32; ++jj) O[jj] += rv * wr[jj];
    }
    float ps = 0.f;
#pragma unroll
    for (int jj = 0; jj < 32; ++jj) ps += O[jj];
    ps += __shfl_xor(ps, 1, 64); ps += __shfl_xor(ps, 2, 64);
    const float mean = ps * (1.f / 128.f);
    float pq = 0.f;
#pragma unroll
    for (int jj = 0; jj < 32; ++jj) { const float d = O[jj] - mean; pq += d * d; }
    pq += __shfl_xor(pq, 1, 64); pq += __shfl_xor(pq, 2, 64);
    const float rstd = rsqrtf(pq * (1.f / 128.f) + 1e-5f);
    __syncthreads(); // everyone done reading shR
    for (int jj = 0; jj < 32; ++jj) {
        const int j = q * 32 + jj;
        shR[s * 128 + j] = (O[jj] - mean) * rstd * g1[j] + b1[j];
    }
    __syncthreads();

    ffn_ln_store(shR, tbuf, W1, W2, g2, b2, out_nb + (size_t)bn * 8192);
}

// ---------------------------------------------------------------------------
// Kernel 3a: per (b, h). self-softmax + att_factor/16 * att_sum; @ x_emb.
// ---------------------------------------------------------------------------
__global__ __launch_bounds__(256) void k_self(
    const float* __restrict__ xemb,            // (128,64,128) fp32
    const float* __restrict__ att_sum,         // (128,4,64,64)
    const float* __restrict__ attf,            // scalar fp32
    float* __restrict__ res_si)                // (128,4,64,128) fp32
{
    const int bh = blockIdx.x;   // b*4 + h
    const int b = bh >> 2;
    const int tid = threadIdx.x;
    __shared__ float xe[64 * 128]; // 32 KB
    __shared__ float A[64 * 64];   // 16 KB

    const float* xp = xemb + (size_t)b * 8192;
    for (int i = tid; i < 8192; i += 256) xe[i] = xp[i];
    __syncthreads();

    const float isc = 0.08838834764831845f; // 1/sqrt(128)
    for (int i = tid; i < 4096; i += 256) {
        const int s = i >> 6, t = i & 63;
        const float* xs = xe + s * 128;
        const float* xt = xe + t * 128;
        float acc = 0.f;
#pragma unroll 8
        for (int d = 0; d < 128; ++d) acc += xs[d] * xt[d];
        A[i] = acc * isc;
    }
    __syncthreads();
    if (tid < 64) {
        float* r = A + tid * 64;
        float m = r[0];
        for (int t = 1; t < 64; ++t) m = fmaxf(m, r[t]);
        float sum = 0.f;
        for (int t = 0; t < 64; ++t) { const float e = __expf(r[t] - m); r[t] = e; sum += e; }
        const float inv = 1.f / sum;
        for (int t = 0; t < 64; ++t) r[t] *= inv;
    }
    __syncthreads();
    const float f = attf[0] * (1.f / 16.f);
    const float* as = att_sum + (size_t)bh * 4096;
    for (int i = tid; i < 4096; i += 256) A[i] += f * as[i];
    __syncthreads();

    float* op = res_si + (size_t)bh * 8192;
    for (int i = tid; i < 8192; i += 256) {
        const int s = i >> 7, d = i & 127;
        const float* ar = A + s * 64;
        float acc = 0.f;
        for (int t = 0; t < 64; ++t) acc += ar[t] * xe[t * 128 + d];
        op[i] = acc;
    }
}

// ---------------------------------------------------------------------------
// Kernel 3b: per b. x1 = cat_h(res_si) @ W_SI; out x = FFN+LN (fp32).
// ---------------------------------------------------------------------------
__global__ __launch_bounds__(256) void k_si_ffn(
    const float* __restrict__ res_si,
    const float* __restrict__ WSI,             // (512,128)
    const float* __restrict__ W1, const float* __restrict__ W2,
    const float* __restrict__ g, const float* __restrict__ bb,
    float* __restrict__ out_x)
{
    const int b = blockIdx.x;
    const int tid = threadIdx.x;
    __shared__ float shX[64 * 128]; // 32 KB
    __shared__ float tbuf[4 * 512]; // 8 KB

    const int s = tid >> 2, q = tid & 3;
    float acc[32];
#pragma unroll
    for (int jj = 0; jj < 32; ++jj) acc[jj] = 0.f;
    const float* rs = res_si + (size_t)b * 4 * 8192;
    for (int h = 0; h < 4; ++h) {
        const float* row = rs + h * 8192 + s * 128;
        const float* wbase = WSI + h * 128 * 128 + q * 32;
        for (int d = 0; d < 128; ++d) {
            const float rv = row[d];
            const float* wr = wbase + d * 128;
#pragma unroll 8
            for (int jj = 0; jj < 32; ++jj) acc[jj] += rv * wr[jj];
        }
    }
    for (int jj = 0; jj < 32; ++jj) shX[s * 128 + q * 32 + jj] = acc[jj];
    __syncthreads();

    ffn_ln_store(shX, tbuf, W1, W2, g, bb, out_x + (size_t)b * 8192);
}

// ---------------------------------------------------------------------------
extern "C" void kernel_launch(void* const* d_in, const int* in_sizes, int n_in,
                              void* d_out, int out_size, void* d_ws, size_t ws_size,
                              hipStream_t stream) {
    const float* x_emb = (const float*)d_in[0];
    const float* nbr   = (const float*)d_in[1];
    const void*  mask  = d_in[2];
    const float* attf  = (const float*)d_in[3];
    const float* Wq    = (const float*)d_in[4];
    const float* Wk    = (const float*)d_in[5];
    const float* Wv    = (const float*)d_in[6];
    const float* Wfc   = (const float*)d_in[7];
    const float* g_mha = (const float*)d_in[8];
    const float* b_mha = (const float*)d_in[9];
    const float* WSI   = (const float*)d_in[10];
    const float* W1s   = (const float*)d_in[11];
    const float* W2s   = (const float*)d_in[12];
    const float* gs    = (const float*)d_in[13];
    const float* bs    = (const float*)d_in[14];
    const float* W1i   = (const float*)d_in[15];
    const float* W2i   = (const float*)d_in[16];
    const float* gi    = (const float*)d_in[17];
    const float* bi    = (const float*)d_in[18];

    // workspace (~25 MB):
    //   [0, 8M)            att_sum fp32 (128*4*64*64)  -- zeroed each call
    //   [8M, 8M+256)       mask-mode flag
    //   [8M+256, +16.8M)   res_si fp32 (128*4*64*128)
    float* att_sum = (float*)d_ws;
    int* mflag = (int*)((char*)d_ws + (size_t)8 * 1024 * 1024);
    float* res_si = (float*)((char*)d_ws + (size_t)8 * 1024 * 1024 + 256);

    float* out_x  = (float*)d_out;                       // output 0: x (fp32)
    float* out_nb = out_x + (size_t)NA * SS * DD;        // output 1: nb (fp32)
    // res (MHA output pre-W_fc) staged in out_nb's storage: exact fp32
    // element-count match (2048*64*128), consumed per-block by k_mha_ffn.
    float* res_ws = out_nb;

    hipMemsetAsync(d_ws, 0, (size_t)NA * HH * SS * SS * sizeof(float), stream);

    k_maskmode<<<1, 256, 0, stream>>>((const unsigned int*)mask, mflag);
    k_attn<<<NA * NN_ * HH, 256, 0, stream>>>(nbr, mask, mflag, Wq, Wk, Wv,
                                              att_sum, res_ws);
    k_mha_ffn<<<NA * NN_, 256, 0, stream>>>(nbr, res_ws, Wfc, g_mha, b_mha,
                                            W1i, W2i, gi, bi, out_nb);
    k_self<<<NA * HH, 256, 0, stream>>>(x_emb, att_sum, attf, res_si);
    k_si_ffn<<<NA, 256, 0, stream>>>(res_si, WSI, W1s, W2s, gs, bs, out_x);
}